// Round 5
// baseline (729.377 us; speedup 1.0000x reference)
//
#include <hip/hip_runtime.h>
#include <math.h>
#include <stdint.h>

#define PI_F 3.14159265358979323846f
#define HALF_PI_F 1.57079632679489662f

// Problem constants: B=32, N=200000, H=1024, W=2048
#define IMG_H 1024
#define IMG_W 2048
#define NB 4    // batches per thread (round 5: 8->4 to fit no-spill MLP)

// Workspace layout:
//   floats [0, 9*B)   : rotation matrices Rm
//   floats [288, 320) : per-batch loss sums
//   floats [320, 352) : per-batch mask counts
//   u32    [352]      : done-block counter (last-block finalize)
//   bytes  [2048, +4MB): NON-overlapping even/odd row-pair RGB565 image:
//     u32 vp2[(y>>1)*W + x] = lo: pix(2k, x), hi: pix(2k+1, x)
//   -> 4 MB: fits per-XCD L2 (verified round 2: FETCH 184MB -> 27MB)

__device__ __forceinline__ float fast_atan2f(float y, float x) {
    float ax = fabsf(x), ay = fabsf(y);
    float mx = fmaxf(ax, ay), mn = fminf(ax, ay);
    float a = __fdividef(mn, mx);
    float s = a * a;
    float r = fmaf(s, -0.01172120f, 0.05265332f);
    r = fmaf(s, r, -0.11643287f);
    r = fmaf(s, r, 0.19354346f);
    r = fmaf(s, r, -0.33262347f);
    r = fmaf(s, r, 0.99997726f);
    r = r * a;
    if (ay > ax) r = HALF_PI_F - r;
    if (x < 0.0f) r = PI_F - r;
    return copysignf(r, y);
}

__device__ __forceinline__ uint32_t q565(float r, float g, float b) {
    uint32_t r5 = min((uint32_t)__float2uint_rn(r * 31.0f), 31u);
    uint32_t g6 = min((uint32_t)__float2uint_rn(g * 63.0f), 63u);
    uint32_t b5 = min((uint32_t)__float2uint_rn(b * 31.0f), 31u);
    return (r5 << 11) | (g6 << 5) | b5;
}

// Pack f32 HWC image -> even/odd row-pair RGB565 u32.
// Round-5 rewrite: one block per row-pair; coalesced float4 global loads ->
// 48 KB LDS -> each thread packs 8 adjacent output words (2x uint4 stores).
// (Old version read at a 48 B/thread divergent stride.)
__global__ __launch_bounds__(256) void bsl_pack_setup(
        const float* __restrict__ img, uint32_t* __restrict__ vp2,
        const float* __restrict__ yaw, const float* __restrict__ pitch,
        const float* __restrict__ roll, float* __restrict__ rm,
        float* __restrict__ sums, float* __restrict__ cnts,
        unsigned* __restrict__ done, int B) {
    __shared__ float lds[2][IMG_W * 3];     // 2 rows * 24 KB
    const int y2 = blockIdx.x;              // 0..511
    const int tid = threadIdx.x;

    if (y2 == 0 && tid < 32) {
        int b = tid;
        if (b == 0) *done = 0u;
        if (b < B) {
            float cr = cosf(roll[b]),  sr = sinf(roll[b]);
            float cp = cosf(pitch[b]), sp = sinf(pitch[b]);
            float cy = cosf(yaw[b]),   sy = sinf(yaw[b]);
            float RX[9] = {1.f, 0.f, 0.f,   0.f, cr, -sr,   0.f, sr,  cr};
            float RY[9] = {cp,  0.f, sp,    0.f, 1.f, 0.f,  -sp, 0.f, cp};
            float RZ[9] = {cy, -sy, 0.f,    sy,  cy, 0.f,   0.f, 0.f, 1.f};
            float A[9], M[9];
            for (int i = 0; i < 3; ++i)
                for (int j = 0; j < 3; ++j) {
                    float s = 0.f;
                    for (int k = 0; k < 3; ++k) s += RZ[i*3+k] * RY[k*3+j];
                    A[i*3+j] = s;
                }
            for (int i = 0; i < 3; ++i)
                for (int j = 0; j < 3; ++j) {
                    float s = 0.f;
                    for (int k = 0; k < 3; ++k) s += A[i*3+k] * RX[k*3+j];
                    M[i*3+j] = s;
                }
            for (int k = 0; k < 9; ++k) rm[b*9+k] = M[k];
            sums[b] = 0.f;
            cnts[b] = 0.f;
        }
    }

    // Stage rows 2*y2 and 2*y2+1 (1536 float4 each), fully coalesced.
    const float4* s0 = (const float4*)(img + (size_t)(2 * y2)     * IMG_W * 3);
    const float4* s1 = (const float4*)(img + (size_t)(2 * y2 + 1) * IMG_W * 3);
    float4* d0 = (float4*)lds[0];
    float4* d1 = (float4*)lds[1];
    #pragma unroll
    for (int i = 0; i < 6; ++i) {
        d0[tid + 256 * i] = s0[tid + 256 * i];
        d1[tid + 256 * i] = s1[tid + 256 * i];
    }
    __syncthreads();

    // Each thread packs 8 adjacent columns.
    const int xb = tid * 8;
    uint32_t w[8];
    #pragma unroll
    for (int j = 0; j < 8; ++j) {
        int x3 = (xb + j) * 3;
        uint32_t lo = q565(lds[0][x3], lds[0][x3+1], lds[0][x3+2]);
        uint32_t hi = q565(lds[1][x3], lds[1][x3+1], lds[1][x3+2]);
        w[j] = lo | (hi << 16);
    }
    uint4* dst = (uint4*)(vp2 + ((size_t)y2 * IMG_W + xb));
    dst[0] = make_uint4(w[0], w[1], w[2], w[3]);
    dst[1] = make_uint4(w[4], w[5], w[6], w[7]);
}

// ---- per-sample setup: compute coords, flags, and issue 4 asm gathers ----
// All outputs are NAMED SCALARS (round-4 lesson: asm ties on array elements
// defeat SROA -> allocas -> scratch round-trips -> 4.7x slowdown).
#define SAMPLE_SETUP(NBI, WXV, WYV, SPV, LA0, LA1, LB0, LB1)                  \
    {                                                                         \
        const int b = b0 + NBI;                                               \
        const float* R = rm + b * 9;        /* block-uniform -> s_load */     \
        const float* T = trans + b * 3;                                       \
        float qx = px - T[0], qy = py - T[1], qz = pz - T[2];                 \
        float vx = R[0]*qx + R[1]*qy + R[2]*qz;                               \
        float vy = R[3]*qx + R[4]*qy + R[5]*qz;                               \
        float vz = R[6]*qx + R[7]*qy + R[8]*qz;                               \
        float rxy   = sqrtf(vx*vx + vy*vy);                                   \
        float theta = fast_atan2f(rxy, vz);     /* [0, pi] */                 \
        float praw  = fast_atan2f(vy, vx);      /* (-pi, pi] */               \
        float xf = fmaf(praw,  -325.949323452f, 1023.5f);                     \
        float yf = fmaf(theta,  325.949323452f, -0.5f);                       \
        float x0f = floorf(xf);                                               \
        float y0f = floorf(yf);                                               \
        WXV = xf - x0f;                                                       \
        WYV = yf - y0f;                                                       \
        float xbf  = fminf(fmaxf(x0f, 0.0f), 2046.0f);                        \
        float yb0f = fminf(fmaxf(y0f,        0.0f), 1023.0f);                 \
        float yb1f = fminf(fmaxf(y0f + 1.0f, 0.0f), 1023.0f);                 \
        int xbi = (int)xbf;                                                   \
        int y0c = (int)yb0f;                                                  \
        int y1c = (int)yb1f;                                                  \
        uint32_t sp = (uint32_t)(y0c & 1) | ((uint32_t)(y1c & 1) << 1);       \
        if (y0f >= 0.0f)     sp |= 4u;      /* vy0 */                         \
        if (y0f <= 1022.0f)  sp |= 8u;      /* vy1 */                         \
        if (x0f >= 0.0f)     sp |= 16u;     /* vx0 */                         \
        if (x0f <= 2046.0f)  sp |= 32u;     /* vx1 */                         \
        if (x0f >= 2047.0f)  sp |= 64u;     /* xhi */                         \
        SPV = sp;                                                             \
        const uint32_t* aA = vp2 + (((y0c >> 1) << 11) + xbi);                \
        const uint32_t* aB = vp2 + (((y1c >> 1) << 11) + xbi);                \
        asm volatile("global_load_dword %0, %1, off"          : "=v"(LA0) : "v"(aA)); \
        asm volatile("global_load_dword %0, %1, off offset:4" : "=v"(LA1) : "v"(aA)); \
        asm volatile("global_load_dword %0, %1, off"          : "=v"(LB0) : "v"(aB)); \
        asm volatile("global_load_dword %0, %1, off offset:4" : "=v"(LB1) : "v"(aB)); \
    }

// ---- per-sample decode (verified logic from rounds 2-4) ----
#define SAMPLE_DECODE(NBI, WXV, WYV, SPV, LA0, LA1, LB0, LB1)                 \
    {                                                                         \
        uint32_t sp = SPV;                                                    \
        float wx = WXV, wy = WYV;                                             \
        bool vy0 = (sp & 4u)  != 0u;                                          \
        bool vy1 = (sp & 8u)  != 0u;                                          \
        bool vx0 = (sp & 16u) != 0u;                                          \
        bool vx1 = (sp & 32u) != 0u;                                          \
        bool xhi = (sp & 64u) != 0u;                                          \
        float omx = 1.0f - wx, omy = 1.0f - wy;                               \
        float w00 = (vx0 & vy0) ? omx * omy : 0.0f;                           \
        float w10 = (vx1 & vy0) ? wx  * omy : 0.0f;                           \
        float w01 = (vx0 & vy1) ? omx * wy  : 0.0f;                           \
        float w11 = (vx1 & vy1) ? wx  * wy  : 0.0f;                           \
        uint32_t sh0 = (sp & 1u) << 4;                                        \
        uint32_t sh1 = (sp & 2u) << 3;                                        \
        uint32_t A0 = xhi ? LA1 : LA0;                                        \
        uint32_t A1 = vx0 ? LA1 : LA0;                                        \
        uint32_t B0 = xhi ? LB1 : LB0;                                        \
        uint32_t B1 = vx0 ? LB1 : LB0;                                        \
        uint32_t t00 = (A0 >> sh0) & 0xffffu;                                 \
        uint32_t t10 = (A1 >> sh0) & 0xffffu;                                 \
        uint32_t t01 = (B0 >> sh1) & 0xffffu;                                 \
        uint32_t t11 = (B1 >> sh1) & 0xffffu;                                 \
        float r00 = (float)(t00 >> 11),        r10 = (float)(t10 >> 11);      \
        float r01 = (float)(t01 >> 11),        r11 = (float)(t11 >> 11);      \
        float g00 = (float)((t00 >> 5) & 63u), g10 = (float)((t10 >> 5) & 63u);\
        float g01 = (float)((t01 >> 5) & 63u), g11 = (float)((t11 >> 5) & 63u);\
        float b00 = (float)(t00 & 31u),        b10 = (float)(t10 & 31u);      \
        float b01 = (float)(t01 & 31u),        b11 = (float)(t11 & 31u);      \
        float srr = r00*w00 + r10*w10 + r01*w01 + r11*w11;                    \
        float sgg = g00*w00 + g10*w10 + g01*w01 + g11*w11;                    \
        float sbb = b00*w00 + b10*w10 + b01*w01 + b11*w11;                    \
        bool m = !((srr == 0.0f) && (sgg == 0.0f) && (sbb == 0.0f));          \
        float d0 = fmaf(srr, 1.0f / 31.0f, -r0);                              \
        float d1 = fmaf(sgg, 1.0f / 63.0f, -r1);                              \
        float d2 = fmaf(sbb, 1.0f / 31.0f, -r2);                              \
        float per = sqrtf(d0*d0 + d1*d1 + d2*d2);                             \
        accs[NBI] += m ? per : 0.0f;                                          \
        cnl[NBI]  += m ? 1.0f : 0.0f;                                         \
    }

__global__ __launch_bounds__(256, 4) void bsl_main(
        const float* __restrict__ xyz,
        const float* __restrict__ rgb,
        const uint32_t* __restrict__ vp2,
        const float* __restrict__ trans,
        const float* __restrict__ rm,
        float* __restrict__ sums,
        float* __restrict__ cnts,
        unsigned* __restrict__ done,
        float* __restrict__ out,
        int n_pts, int B) {
    const int b0 = blockIdx.y * NB;
    const int tid = threadIdx.x;
    const int n = blockIdx.x * 256 + tid;

    float accs[NB], cnl[NB];
    #pragma unroll
    for (int nb = 0; nb < NB; ++nb) { accs[nb] = 0.f; cnl[nb] = 0.f; }

    if (n < n_pts) {
        // nontemporal: don't let the point streams evict the image from L2
        float px = __builtin_nontemporal_load(&xyz[3*n+0]);
        float py = __builtin_nontemporal_load(&xyz[3*n+1]);
        float pz = __builtin_nontemporal_load(&xyz[3*n+2]);
        float r0 = __builtin_nontemporal_load(&rgb[3*n+0]);
        float r1 = __builtin_nontemporal_load(&rgb[3*n+1]);
        float r2 = __builtin_nontemporal_load(&rgb[3*n+2]);

        float wx0, wy0, wx1, wy1, wx2, wy2, wx3, wy3;
        uint32_t sp0, sp1, sp2, sp3;
        uint32_t a00, a01, a02, a03;
        uint32_t a10, a11, a12, a13;
        uint32_t a20, a21, a22, a23;
        uint32_t a30, a31, a32, a33;

        // Phase 1: 16 volatile-asm gathers issued back-to-back (true MLP).
        SAMPLE_SETUP(0, wx0, wy0, sp0, a00, a01, a02, a03)
        SAMPLE_SETUP(1, wx1, wy1, sp1, a10, a11, a12, a13)
        SAMPLE_SETUP(2, wx2, wy2, sp2, a20, a21, a22, a23)
        SAMPLE_SETUP(3, wx3, wy3, sp3, a30, a31, a32, a33)

        // Stage 1: oldest 8 of our 16 gathers done (any older point-stream
        // loads retire first -- in-order vmcnt -- so vmcnt(8) still covers).
        asm volatile("s_waitcnt vmcnt(8)"
            : "+v"(a00), "+v"(a01), "+v"(a02), "+v"(a03),
              "+v"(a10), "+v"(a11), "+v"(a12), "+v"(a13));
        __builtin_amdgcn_sched_barrier(0);
        SAMPLE_DECODE(0, wx0, wy0, sp0, a00, a01, a02, a03)
        SAMPLE_DECODE(1, wx1, wy1, sp1, a10, a11, a12, a13)

        asm volatile("s_waitcnt vmcnt(0)"
            : "+v"(a20), "+v"(a21), "+v"(a22), "+v"(a23),
              "+v"(a30), "+v"(a31), "+v"(a32), "+v"(a33));
        __builtin_amdgcn_sched_barrier(0);
        SAMPLE_DECODE(2, wx2, wy2, sp2, a20, a21, a22, a23)
        SAMPLE_DECODE(3, wx3, wy3, sp3, a30, a31, a32, a33)
    }

    // wave(64) shuffle reduce per batch, then LDS across 4 waves, then atomics
    __shared__ float lsum[4][NB], lcnt[4][NB];
    int wid = tid >> 6;
    int lane = tid & 63;
    #pragma unroll
    for (int nb = 0; nb < NB; ++nb) {
        float a = accs[nb], c = cnl[nb];
        #pragma unroll
        for (int off = 32; off > 0; off >>= 1) {
            a += __shfl_down(a, off, 64);
            c += __shfl_down(c, off, 64);
        }
        if (lane == 0) { lsum[wid][nb] = a; lcnt[wid][nb] = c; }
    }
    __syncthreads();
    if (tid < NB * 2) {
        int nb = tid & (NB - 1);
        int k = tid >> 2;   // 0 = sum, 1 = cnt  (NB = 4)
        float v = 0.f;
        #pragma unroll
        for (int w = 0; w < 4; ++w) v += k ? lcnt[w][nb] : lsum[w][nb];
        atomicAdd(k ? &cnts[b0 + nb] : &sums[b0 + nb], v);
    }

    // Last-block finalize (replaces a separate kernel launch).
    __threadfence();
    __shared__ bool isLast;
    if (tid == 0) {
        unsigned prev = atomicAdd(done, 1u);
        isLast = (prev == gridDim.x * gridDim.y - 1u);
    }
    __syncthreads();
    if (isLast && tid < 64) {
        __threadfence();    // acquire side
        int b = tid;
        float loss = 0.f;
        if (b < B) {
            float s = __hip_atomic_load(&sums[b], __ATOMIC_RELAXED, __HIP_MEMORY_SCOPE_AGENT);
            float c = __hip_atomic_load(&cnts[b], __ATOMIC_RELAXED, __HIP_MEMORY_SCOPE_AGENT);
            loss = s / c;
            out[1 + b] = loss;
        }
        #pragma unroll
        for (int off = 32; off > 0; off >>= 1)
            loss += __shfl_down(loss, off, 64);
        if (b == 0) out[0] = loss;
    }
}

extern "C" void kernel_launch(void* const* d_in, const int* in_sizes, int n_in,
                              void* d_out, int out_size, void* d_ws, size_t ws_size,
                              hipStream_t stream) {
    const float* xyz   = (const float*)d_in[0];
    const float* rgb   = (const float*)d_in[1];
    const float* img   = (const float*)d_in[2];
    const float* trans = (const float*)d_in[3];
    const float* yaw   = (const float*)d_in[4];
    const float* pitch = (const float*)d_in[5];
    const float* roll  = (const float*)d_in[6];
    float* out = (float*)d_out;

    const int n_pts = in_sizes[0] / 3;      // 200000
    const int B     = in_sizes[3] / 3;      // 32

    float* ws   = (float*)d_ws;
    float* rm   = ws;                           // 9*B floats
    float* sums = ws + 9 * B;                   // B floats
    float* cnts = ws + 10 * B;                  // B floats
    unsigned* done = (unsigned*)(ws + 11 * B);  // 1 u32
    uint32_t* vp2 = (uint32_t*)((char*)d_ws + 2048);  // 4 MB

    bsl_pack_setup<<<IMG_H / 2, 256, 0, stream>>>(
        img, vp2, yaw, pitch, roll, rm, sums, cnts, done, B);

    dim3 grid((n_pts + 255) / 256, B / NB);
    bsl_main<<<grid, 256, 0, stream>>>(xyz, rgb, vp2, trans, rm, sums, cnts,
                                       done, out, n_pts, B);
}

// Round 6
// 395.142 us; speedup vs baseline: 1.8459x; 1.8459x over previous
//
#include <hip/hip_runtime.h>
#include <math.h>
#include <stdint.h>

#define PI_F 3.14159265358979323846f
#define HALF_PI_F 1.57079632679489662f

// Problem constants: B=32, N=200000, H=1024, W=2048
#define IMG_H 1024
#define IMG_W 2048
#define NB 8    // batches per thread (round-3 proven config)

// Workspace layout:
//   floats [0, 9*B)   : rotation matrices Rm
//   floats [288, 320) : per-batch loss sums
//   floats [320, 352) : per-batch mask counts
//   u32    [352]      : done-block counter (last-block finalize)
//   bytes  [2048, +4MB): NON-overlapping even/odd row-pair RGB565 image:
//     u32 vp2[(y>>1)*W + x] = lo: pix(2k, x), hi: pix(2k+1, x)
//   -> 4 MB: fits per-XCD L2 (verified round 2: FETCH 184MB -> 27MB)
//
// Session ledger:
//   r1-r3: compiler re-fuses phase-split loops, keeps ~2 gathers in flight
//          (VGPR stayed 32-36). bsl_main ~67-70us regardless.
//   r4-r5: inline-asm gather forcing -> SROA/RA collapse -> scratch ->
//          4.7x / 10x regressions. ABANDONED: do not fight the scheduler
//          with asm-tied loads in this kernel.
//   r6: exact r3 bsl_main + LDS-coalesced pack + fused finalize (2 launches).

// 8-byte pair of adjacent vp2 words, 4-byte aligned.
struct __attribute__((packed, aligned(4))) U2 { uint32_t a, b; };

__device__ __forceinline__ float fast_atan2f(float y, float x) {
    float ax = fabsf(x), ay = fabsf(y);
    float mx = fmaxf(ax, ay), mn = fminf(ax, ay);
    float a = __fdividef(mn, mx);
    float s = a * a;
    float r = fmaf(s, -0.01172120f, 0.05265332f);
    r = fmaf(s, r, -0.11643287f);
    r = fmaf(s, r, 0.19354346f);
    r = fmaf(s, r, -0.33262347f);
    r = fmaf(s, r, 0.99997726f);
    r = r * a;
    if (ay > ax) r = HALF_PI_F - r;
    if (x < 0.0f) r = PI_F - r;
    return copysignf(r, y);
}

__device__ __forceinline__ uint32_t q565(float r, float g, float b) {
    uint32_t r5 = min((uint32_t)__float2uint_rn(r * 31.0f), 31u);
    uint32_t g6 = min((uint32_t)__float2uint_rn(g * 63.0f), 63u);
    uint32_t b5 = min((uint32_t)__float2uint_rn(b * 31.0f), 31u);
    return (r5 << 11) | (g6 << 5) | b5;
}

// Pack f32 HWC image -> even/odd row-pair RGB565 u32.
// One block per row-pair; coalesced float4 loads -> 48 KB LDS -> each thread
// packs 8 adjacent output words (2x uint4 stores). Block 0 also does setup.
__global__ __launch_bounds__(256) void bsl_pack_setup(
        const float* __restrict__ img, uint32_t* __restrict__ vp2,
        const float* __restrict__ yaw, const float* __restrict__ pitch,
        const float* __restrict__ roll, float* __restrict__ rm,
        float* __restrict__ sums, float* __restrict__ cnts,
        unsigned* __restrict__ done, int B) {
    __shared__ float lds[2][IMG_W * 3];     // 2 rows * 24 KB
    const int y2 = blockIdx.x;              // 0..511
    const int tid = threadIdx.x;

    if (y2 == 0 && tid < 32) {
        int b = tid;
        if (b == 0) *done = 0u;
        if (b < B) {
            float cr = cosf(roll[b]),  sr = sinf(roll[b]);
            float cp = cosf(pitch[b]), sp = sinf(pitch[b]);
            float cy = cosf(yaw[b]),   sy = sinf(yaw[b]);
            float RX[9] = {1.f, 0.f, 0.f,   0.f, cr, -sr,   0.f, sr,  cr};
            float RY[9] = {cp,  0.f, sp,    0.f, 1.f, 0.f,  -sp, 0.f, cp};
            float RZ[9] = {cy, -sy, 0.f,    sy,  cy, 0.f,   0.f, 0.f, 1.f};
            float A[9], M[9];
            for (int i = 0; i < 3; ++i)
                for (int j = 0; j < 3; ++j) {
                    float s = 0.f;
                    for (int k = 0; k < 3; ++k) s += RZ[i*3+k] * RY[k*3+j];
                    A[i*3+j] = s;
                }
            for (int i = 0; i < 3; ++i)
                for (int j = 0; j < 3; ++j) {
                    float s = 0.f;
                    for (int k = 0; k < 3; ++k) s += A[i*3+k] * RX[k*3+j];
                    M[i*3+j] = s;
                }
            for (int k = 0; k < 9; ++k) rm[b*9+k] = M[k];
            sums[b] = 0.f;
            cnts[b] = 0.f;
        }
    }

    // Stage rows 2*y2 and 2*y2+1 (1536 float4 each), fully coalesced.
    const float4* s0 = (const float4*)(img + (size_t)(2 * y2)     * IMG_W * 3);
    const float4* s1 = (const float4*)(img + (size_t)(2 * y2 + 1) * IMG_W * 3);
    float4* d0 = (float4*)lds[0];
    float4* d1 = (float4*)lds[1];
    #pragma unroll
    for (int i = 0; i < 6; ++i) {
        d0[tid + 256 * i] = s0[tid + 256 * i];
        d1[tid + 256 * i] = s1[tid + 256 * i];
    }
    __syncthreads();

    // Each thread packs 8 adjacent columns.
    const int xb = tid * 8;
    uint32_t w[8];
    #pragma unroll
    for (int j = 0; j < 8; ++j) {
        int x3 = (xb + j) * 3;
        uint32_t lo = q565(lds[0][x3], lds[0][x3+1], lds[0][x3+2]);
        uint32_t hi = q565(lds[1][x3], lds[1][x3+1], lds[1][x3+2]);
        w[j] = lo | (hi << 16);
    }
    uint4* dst = (uint4*)(vp2 + ((size_t)y2 * IMG_W + xb));
    dst[0] = make_uint4(w[0], w[1], w[2], w[3]);
    dst[1] = make_uint4(w[4], w[5], w[6], w[7]);
}

// EXACT round-3 main kernel (67.5us, VGPR 36) + fused last-block finalize.
__global__ __launch_bounds__(256, 4) void bsl_main(
        const float* __restrict__ xyz,
        const float* __restrict__ rgb,
        const uint32_t* __restrict__ vp2,
        const float* __restrict__ trans,
        const float* __restrict__ rm,
        float* __restrict__ sums,
        float* __restrict__ cnts,
        unsigned* __restrict__ done,
        float* __restrict__ out,
        int n_pts, int B) {
    const int b0 = blockIdx.y * NB;
    const int tid = threadIdx.x;
    const int n = blockIdx.x * 256 + tid;

    float accs[NB], cnl[NB];
    #pragma unroll
    for (int nb = 0; nb < NB; ++nb) { accs[nb] = 0.f; cnl[nb] = 0.f; }

    if (n < n_pts) {
        // nontemporal: don't let the point streams evict the image from L2
        float px = __builtin_nontemporal_load(&xyz[3*n+0]);
        float py = __builtin_nontemporal_load(&xyz[3*n+1]);
        float pz = __builtin_nontemporal_load(&xyz[3*n+2]);
        float r0 = __builtin_nontemporal_load(&rgb[3*n+0]);
        float r1 = __builtin_nontemporal_load(&rgb[3*n+1]);
        float r2 = __builtin_nontemporal_load(&rgb[3*n+2]);

        // Phase 1: compute coords for all NB batches, issue pair loads.
        float xfa[NB], wxa[NB], wya[NB];
        uint32_t shp[NB];
        uint32_t pAa[NB], pAb[NB], pBa[NB], pBb[NB];
        #pragma unroll
        for (int nb = 0; nb < NB; ++nb) {
            const int b = b0 + nb;
            const float* R = rm + b * 9;        // block-uniform -> s_load
            const float* T = trans + b * 3;
            float qx = px - T[0], qy = py - T[1], qz = pz - T[2];

            float vx = R[0]*qx + R[1]*qy + R[2]*qz;
            float vy = R[3]*qx + R[4]*qy + R[5]*qz;
            float vz = R[6]*qx + R[7]*qy + R[8]*qz;

            float rxy   = sqrtf(vx*vx + vy*vy);
            float theta = fast_atan2f(rxy, vz);     // [0, pi]
            float praw  = fast_atan2f(vy, vx);      // (-pi, pi]

            // xf = 1023.5 - 1024*praw/pi ; yf = 1024*theta/pi - 0.5
            float xf = fmaf(praw,  -325.949323452f, 1023.5f);
            float yf = fmaf(theta,  325.949323452f, -0.5f);

            float x0f = floorf(xf);
            float y0f = floorf(yf);
            xfa[nb] = xf;
            wxa[nb] = xf - x0f;
            wya[nb] = yf - y0f;

            // base column clamped to [0,2046] so pair (xb, xb+1) is in-bounds
            float xbf  = fminf(fmaxf(x0f, 0.0f), 2046.0f);
            float yb0f = fminf(fmaxf(y0f,        0.0f), 1023.0f);
            float yb1f = fminf(fmaxf(y0f + 1.0f, 0.0f), 1023.0f);
            int xb  = (int)xbf;
            int y0c = (int)yb0f;
            int y1c = (int)yb1f;
            uint32_t sp = ((uint32_t)(y0c & 1) << 4) | ((uint32_t)(y1c & 1) << 12);
            if (y0f >= 0.0f)    sp |= 1u << 24;     // vy0
            if (y0f <= 1022.0f) sp |= 1u << 25;     // vy1
            shp[nb] = sp;

            // row-pair words: vp2[(y>>1)*2048 + xb], cols xb, xb+1
            U2 tA = *(const U2*)(vp2 + (((y0c >> 1) << 11) + xb));
            U2 tB = *(const U2*)(vp2 + (((y1c >> 1) << 11) + xb));
            pAa[nb] = tA.a; pAb[nb] = tA.b;
            pBa[nb] = tB.a; pBb[nb] = tB.b;
        }

        #pragma unroll
        for (int nb = 0; nb < NB; ++nb) {
            asm volatile("" : "+v"(pAa[nb]), "+v"(pAb[nb]),
                             "+v"(pBa[nb]), "+v"(pBb[nb]) :: "memory");
        }

        // Phase 2: decode + blend + accumulate.
        #pragma unroll
        for (int nb = 0; nb < NB; ++nb) {
            float xf = xfa[nb];
            float x0f = floorf(xf);
            float wx = wxa[nb], wy = wya[nb];

            bool vx0 = (x0f >= 0.0f);       // x0 valid
            bool vx1 = (x0f <= 2046.0f);    // x0+1 valid
            uint32_t sp = shp[nb];
            bool vy0 = (sp & (1u << 24)) != 0u;
            bool vy1 = (sp & (1u << 25)) != 0u;

            float omx = 1.0f - wx, omy = 1.0f - wy;
            float w00 = (vx0 & vy0) ? omx * omy : 0.0f;
            float w10 = (vx1 & vy0) ? wx  * omy : 0.0f;
            float w01 = (vx0 & vy1) ? omx * wy  : 0.0f;
            float w11 = (vx1 & vy1) ? wx  * wy  : 0.0f;

            uint32_t sh0 = sp & 0xffu;
            uint32_t sh1 = (sp >> 8) & 0xffu;

            // column fixups:
            // x0==2047: base clamped to 2046 -> col x0 is .b (x1 weights are 0)
            // x0==-1:   base 0 -> col x1 is .a (x0 weights are 0)
            bool xhi = (x0f >= 2047.0f);
            uint32_t A0 = xhi ? pAb[nb] : pAa[nb];    // (y0 row-pair, col x0)
            uint32_t A1 = vx0 ? pAb[nb] : pAa[nb];    // (y0 row-pair, col x1)
            uint32_t B0 = xhi ? pBb[nb] : pBa[nb];    // (y1 row-pair, col x0)
            uint32_t B1 = vx0 ? pBb[nb] : pBa[nb];    // (y1 row-pair, col x1)

            uint32_t t00 = (A0 >> sh0) & 0xffffu;
            uint32_t t10 = (A1 >> sh0) & 0xffffu;
            uint32_t t01 = (B0 >> sh1) & 0xffffu;
            uint32_t t11 = (B1 >> sh1) & 0xffffu;

            // integer-valued float channels; fold 1/31,1/63 into the final fma
            float r00 = (float)(t00 >> 11),        r10 = (float)(t10 >> 11);
            float r01 = (float)(t01 >> 11),        r11 = (float)(t11 >> 11);
            float g00 = (float)((t00 >> 5) & 63u), g10 = (float)((t10 >> 5) & 63u);
            float g01 = (float)((t01 >> 5) & 63u), g11 = (float)((t11 >> 5) & 63u);
            float b00 = (float)(t00 & 31u),        b10 = (float)(t10 & 31u);
            float b01 = (float)(t01 & 31u),        b11 = (float)(t11 & 31u);

            float sr = r00*w00 + r10*w10 + r01*w01 + r11*w11;
            float sg = g00*w00 + g10*w10 + g01*w01 + g11*w11;
            float sb = b00*w00 + b10*w10 + b01*w01 + b11*w11;

            bool m = !((sr == 0.0f) && (sg == 0.0f) && (sb == 0.0f));

            float d0 = fmaf(sr, 1.0f / 31.0f, -r0);
            float d1 = fmaf(sg, 1.0f / 63.0f, -r1);
            float d2 = fmaf(sb, 1.0f / 31.0f, -r2);
            float per = sqrtf(d0*d0 + d1*d1 + d2*d2);

            accs[nb] += m ? per : 0.0f;
            cnl[nb]  += m ? 1.0f : 0.0f;
        }
    }

    // wave(64) shuffle reduce per batch, then LDS across 4 waves, then atomics
    __shared__ float lsum[4][NB], lcnt[4][NB];
    int wid = tid >> 6;
    int lane = tid & 63;
    #pragma unroll
    for (int nb = 0; nb < NB; ++nb) {
        float a = accs[nb], c = cnl[nb];
        #pragma unroll
        for (int off = 32; off > 0; off >>= 1) {
            a += __shfl_down(a, off, 64);
            c += __shfl_down(c, off, 64);
        }
        if (lane == 0) { lsum[wid][nb] = a; lcnt[wid][nb] = c; }
    }
    __syncthreads();
    if (tid < NB * 2) {
        int nb = tid & (NB - 1);
        int k = tid >> 3;   // 0 = sum, 1 = cnt  (NB = 8)
        float v = 0.f;
        #pragma unroll
        for (int w = 0; w < 4; ++w) v += k ? lcnt[w][nb] : lsum[w][nb];
        atomicAdd(k ? &cnts[b0 + nb] : &sums[b0 + nb], v);
    }

    // Last-block finalize (replaces a separate kernel launch; verified in
    // rounds 4-5).
    __threadfence();
    __shared__ bool isLast;
    if (tid == 0) {
        unsigned prev = atomicAdd(done, 1u);
        isLast = (prev == gridDim.x * gridDim.y - 1u);
    }
    __syncthreads();
    if (isLast && tid < 64) {
        __threadfence();    // acquire side
        int b = tid;
        float loss = 0.f;
        if (b < B) {
            float s = __hip_atomic_load(&sums[b], __ATOMIC_RELAXED, __HIP_MEMORY_SCOPE_AGENT);
            float c = __hip_atomic_load(&cnts[b], __ATOMIC_RELAXED, __HIP_MEMORY_SCOPE_AGENT);
            loss = s / c;
            out[1 + b] = loss;
        }
        #pragma unroll
        for (int off = 32; off > 0; off >>= 1)
            loss += __shfl_down(loss, off, 64);
        if (b == 0) out[0] = loss;
    }
}

extern "C" void kernel_launch(void* const* d_in, const int* in_sizes, int n_in,
                              void* d_out, int out_size, void* d_ws, size_t ws_size,
                              hipStream_t stream) {
    const float* xyz   = (const float*)d_in[0];
    const float* rgb   = (const float*)d_in[1];
    const float* img   = (const float*)d_in[2];
    const float* trans = (const float*)d_in[3];
    const float* yaw   = (const float*)d_in[4];
    const float* pitch = (const float*)d_in[5];
    const float* roll  = (const float*)d_in[6];
    float* out = (float*)d_out;

    const int n_pts = in_sizes[0] / 3;      // 200000
    const int B     = in_sizes[3] / 3;      // 32

    float* ws   = (float*)d_ws;
    float* rm   = ws;                           // 9*B floats
    float* sums = ws + 9 * B;                   // B floats
    float* cnts = ws + 10 * B;                  // B floats
    unsigned* done = (unsigned*)(ws + 11 * B);  // 1 u32
    uint32_t* vp2 = (uint32_t*)((char*)d_ws + 2048);  // 4 MB

    bsl_pack_setup<<<IMG_H / 2, 256, 0, stream>>>(
        img, vp2, yaw, pitch, roll, rm, sums, cnts, done, B);

    dim3 grid((n_pts + 255) / 256, B / NB);
    bsl_main<<<grid, 256, 0, stream>>>(xyz, rgb, vp2, trans, rm, sums, cnts,
                                       done, out, n_pts, B);
}

// Round 7
// 148.689 us; speedup vs baseline: 4.9054x; 2.6575x over previous
//
#include <hip/hip_runtime.h>
#include <math.h>
#include <stdint.h>

#define PI_F 3.14159265358979323846f
#define HALF_PI_F 1.57079632679489662f

// Problem constants: B=32, N=200000, H=1024, W=2048
#define IMG_H 1024
#define IMG_W 2048
#define NB 8    // batches per thread (round-3 proven config)

// Workspace layout:
//   floats [0, 9*B)   : rotation matrices Rm
//   floats [288, 320) : per-batch loss sums
//   floats [320, 352) : per-batch mask counts
//   bytes  [2048, +4MB): NON-overlapping even/odd row-pair RGB565 image:
//     u32 vp2[(y>>1)*W + x] = lo: pix(2k, x), hi: pix(2k+1, x)
//   -> 4 MB: fits per-XCD L2 (verified round 2: FETCH 184MB -> 27MB)
//
// Session ledger:
//   r1-r3: phase-split / fence attempts -> compiler re-fuses, ~2 gathers in
//          flight (VGPR 32-36), bsl_main ~67-70us regardless. FETCH fix
//          (8MB->4MB image) was the real win of r2.
//   r4-r5: inline-asm gather forcing -> RA collapse -> scratch: ABANDONED.
//   r4/r6: fused last-block finalize (per-block __threadfence + done-atomic)
//          degrades L2 service globally: bsl_main 67->320us at identical
//          FETCH/VGPR. ABANDONED: keep finalize as a separate kernel.
//   r7: consolidation = r3 bsl_main (exact) + LDS pack + separate finalize.

// 8-byte pair of adjacent vp2 words, 4-byte aligned.
struct __attribute__((packed, aligned(4))) U2 { uint32_t a, b; };

__device__ __forceinline__ float fast_atan2f(float y, float x) {
    float ax = fabsf(x), ay = fabsf(y);
    float mx = fmaxf(ax, ay), mn = fminf(ax, ay);
    float a = __fdividef(mn, mx);
    float s = a * a;
    float r = fmaf(s, -0.01172120f, 0.05265332f);
    r = fmaf(s, r, -0.11643287f);
    r = fmaf(s, r, 0.19354346f);
    r = fmaf(s, r, -0.33262347f);
    r = fmaf(s, r, 0.99997726f);
    r = r * a;
    if (ay > ax) r = HALF_PI_F - r;
    if (x < 0.0f) r = PI_F - r;
    return copysignf(r, y);
}

__device__ __forceinline__ uint32_t q565(float r, float g, float b) {
    uint32_t r5 = min((uint32_t)__float2uint_rn(r * 31.0f), 31u);
    uint32_t g6 = min((uint32_t)__float2uint_rn(g * 63.0f), 63u);
    uint32_t b5 = min((uint32_t)__float2uint_rn(b * 31.0f), 31u);
    return (r5 << 11) | (g6 << 5) | b5;
}

// Pack f32 HWC image -> even/odd row-pair RGB565 u32.
// One block per row-pair; coalesced float4 loads -> 48 KB LDS -> each thread
// packs 8 adjacent output words (2x uint4 stores). Block 0 also does setup.
__global__ __launch_bounds__(256) void bsl_pack_setup(
        const float* __restrict__ img, uint32_t* __restrict__ vp2,
        const float* __restrict__ yaw, const float* __restrict__ pitch,
        const float* __restrict__ roll, float* __restrict__ rm,
        float* __restrict__ sums, float* __restrict__ cnts, int B) {
    __shared__ float lds[2][IMG_W * 3];     // 2 rows * 24 KB
    const int y2 = blockIdx.x;              // 0..511
    const int tid = threadIdx.x;

    if (y2 == 0 && tid < 32) {
        int b = tid;
        if (b < B) {
            float cr = cosf(roll[b]),  sr = sinf(roll[b]);
            float cp = cosf(pitch[b]), sp = sinf(pitch[b]);
            float cy = cosf(yaw[b]),   sy = sinf(yaw[b]);
            float RX[9] = {1.f, 0.f, 0.f,   0.f, cr, -sr,   0.f, sr,  cr};
            float RY[9] = {cp,  0.f, sp,    0.f, 1.f, 0.f,  -sp, 0.f, cp};
            float RZ[9] = {cy, -sy, 0.f,    sy,  cy, 0.f,   0.f, 0.f, 1.f};
            float A[9], M[9];
            for (int i = 0; i < 3; ++i)
                for (int j = 0; j < 3; ++j) {
                    float s = 0.f;
                    for (int k = 0; k < 3; ++k) s += RZ[i*3+k] * RY[k*3+j];
                    A[i*3+j] = s;
                }
            for (int i = 0; i < 3; ++i)
                for (int j = 0; j < 3; ++j) {
                    float s = 0.f;
                    for (int k = 0; k < 3; ++k) s += A[i*3+k] * RX[k*3+j];
                    M[i*3+j] = s;
                }
            for (int k = 0; k < 9; ++k) rm[b*9+k] = M[k];
            sums[b] = 0.f;
            cnts[b] = 0.f;
        }
    }

    // Stage rows 2*y2 and 2*y2+1 (1536 float4 each), fully coalesced.
    const float4* s0 = (const float4*)(img + (size_t)(2 * y2)     * IMG_W * 3);
    const float4* s1 = (const float4*)(img + (size_t)(2 * y2 + 1) * IMG_W * 3);
    float4* d0 = (float4*)lds[0];
    float4* d1 = (float4*)lds[1];
    #pragma unroll
    for (int i = 0; i < 6; ++i) {
        d0[tid + 256 * i] = s0[tid + 256 * i];
        d1[tid + 256 * i] = s1[tid + 256 * i];
    }
    __syncthreads();

    // Each thread packs 8 adjacent columns.
    const int xb = tid * 8;
    uint32_t w[8];
    #pragma unroll
    for (int j = 0; j < 8; ++j) {
        int x3 = (xb + j) * 3;
        uint32_t lo = q565(lds[0][x3], lds[0][x3+1], lds[0][x3+2]);
        uint32_t hi = q565(lds[1][x3], lds[1][x3+1], lds[1][x3+2]);
        w[j] = lo | (hi << 16);
    }
    uint4* dst = (uint4*)(vp2 + ((size_t)y2 * IMG_W + xb));
    dst[0] = make_uint4(w[0], w[1], w[2], w[3]);
    dst[1] = make_uint4(w[4], w[5], w[6], w[7]);
}

// EXACT round-3 main kernel (measured 67.5us, VGPR 36). No finalize fused.
__global__ __launch_bounds__(256, 4) void bsl_main(
        const float* __restrict__ xyz,
        const float* __restrict__ rgb,
        const uint32_t* __restrict__ vp2,
        const float* __restrict__ trans,
        const float* __restrict__ rm,
        float* __restrict__ sums,
        float* __restrict__ cnts,
        int n_pts) {
    const int b0 = blockIdx.y * NB;
    const int tid = threadIdx.x;
    const int n = blockIdx.x * 256 + tid;

    float accs[NB], cnl[NB];
    #pragma unroll
    for (int nb = 0; nb < NB; ++nb) { accs[nb] = 0.f; cnl[nb] = 0.f; }

    if (n < n_pts) {
        // nontemporal: don't let the point streams evict the image from L2
        float px = __builtin_nontemporal_load(&xyz[3*n+0]);
        float py = __builtin_nontemporal_load(&xyz[3*n+1]);
        float pz = __builtin_nontemporal_load(&xyz[3*n+2]);
        float r0 = __builtin_nontemporal_load(&rgb[3*n+0]);
        float r1 = __builtin_nontemporal_load(&rgb[3*n+1]);
        float r2 = __builtin_nontemporal_load(&rgb[3*n+2]);

        // Phase 1: compute coords for all NB batches, issue pair loads.
        float xfa[NB], wxa[NB], wya[NB];
        uint32_t shp[NB];
        uint32_t pAa[NB], pAb[NB], pBa[NB], pBb[NB];
        #pragma unroll
        for (int nb = 0; nb < NB; ++nb) {
            const int b = b0 + nb;
            const float* R = rm + b * 9;        // block-uniform -> s_load
            const float* T = trans + b * 3;
            float qx = px - T[0], qy = py - T[1], qz = pz - T[2];

            float vx = R[0]*qx + R[1]*qy + R[2]*qz;
            float vy = R[3]*qx + R[4]*qy + R[5]*qz;
            float vz = R[6]*qx + R[7]*qy + R[8]*qz;

            float rxy   = sqrtf(vx*vx + vy*vy);
            float theta = fast_atan2f(rxy, vz);     // [0, pi]
            float praw  = fast_atan2f(vy, vx);      // (-pi, pi]

            // xf = 1023.5 - 1024*praw/pi ; yf = 1024*theta/pi - 0.5
            float xf = fmaf(praw,  -325.949323452f, 1023.5f);
            float yf = fmaf(theta,  325.949323452f, -0.5f);

            float x0f = floorf(xf);
            float y0f = floorf(yf);
            xfa[nb] = xf;
            wxa[nb] = xf - x0f;
            wya[nb] = yf - y0f;

            // base column clamped to [0,2046] so pair (xb, xb+1) is in-bounds
            float xbf  = fminf(fmaxf(x0f, 0.0f), 2046.0f);
            float yb0f = fminf(fmaxf(y0f,        0.0f), 1023.0f);
            float yb1f = fminf(fmaxf(y0f + 1.0f, 0.0f), 1023.0f);
            int xb  = (int)xbf;
            int y0c = (int)yb0f;
            int y1c = (int)yb1f;
            uint32_t sp = ((uint32_t)(y0c & 1) << 4) | ((uint32_t)(y1c & 1) << 12);
            if (y0f >= 0.0f)    sp |= 1u << 24;     // vy0
            if (y0f <= 1022.0f) sp |= 1u << 25;     // vy1
            shp[nb] = sp;

            // row-pair words: vp2[(y>>1)*2048 + xb], cols xb, xb+1
            U2 tA = *(const U2*)(vp2 + (((y0c >> 1) << 11) + xb));
            U2 tB = *(const U2*)(vp2 + (((y1c >> 1) << 11) + xb));
            pAa[nb] = tA.a; pAb[nb] = tA.b;
            pBa[nb] = tB.a; pBb[nb] = tB.b;
        }

        #pragma unroll
        for (int nb = 0; nb < NB; ++nb) {
            asm volatile("" : "+v"(pAa[nb]), "+v"(pAb[nb]),
                             "+v"(pBa[nb]), "+v"(pBb[nb]) :: "memory");
        }

        // Phase 2: decode + blend + accumulate.
        #pragma unroll
        for (int nb = 0; nb < NB; ++nb) {
            float xf = xfa[nb];
            float x0f = floorf(xf);
            float wx = wxa[nb], wy = wya[nb];

            bool vx0 = (x0f >= 0.0f);       // x0 valid
            bool vx1 = (x0f <= 2046.0f);    // x0+1 valid
            uint32_t sp = shp[nb];
            bool vy0 = (sp & (1u << 24)) != 0u;
            bool vy1 = (sp & (1u << 25)) != 0u;

            float omx = 1.0f - wx, omy = 1.0f - wy;
            float w00 = (vx0 & vy0) ? omx * omy : 0.0f;
            float w10 = (vx1 & vy0) ? wx  * omy : 0.0f;
            float w01 = (vx0 & vy1) ? omx * wy  : 0.0f;
            float w11 = (vx1 & vy1) ? wx  * wy  : 0.0f;

            uint32_t sh0 = sp & 0xffu;
            uint32_t sh1 = (sp >> 8) & 0xffu;

            // column fixups:
            // x0==2047: base clamped to 2046 -> col x0 is .b (x1 weights are 0)
            // x0==-1:   base 0 -> col x1 is .a (x0 weights are 0)
            bool xhi = (x0f >= 2047.0f);
            uint32_t A0 = xhi ? pAb[nb] : pAa[nb];    // (y0 row-pair, col x0)
            uint32_t A1 = vx0 ? pAb[nb] : pAa[nb];    // (y0 row-pair, col x1)
            uint32_t B0 = xhi ? pBb[nb] : pBa[nb];    // (y1 row-pair, col x0)
            uint32_t B1 = vx0 ? pBb[nb] : pBa[nb];    // (y1 row-pair, col x1)

            uint32_t t00 = (A0 >> sh0) & 0xffffu;
            uint32_t t10 = (A1 >> sh0) & 0xffffu;
            uint32_t t01 = (B0 >> sh1) & 0xffffu;
            uint32_t t11 = (B1 >> sh1) & 0xffffu;

            // integer-valued float channels; fold 1/31,1/63 into the final fma
            float r00 = (float)(t00 >> 11),        r10 = (float)(t10 >> 11);
            float r01 = (float)(t01 >> 11),        r11 = (float)(t11 >> 11);
            float g00 = (float)((t00 >> 5) & 63u), g10 = (float)((t10 >> 5) & 63u);
            float g01 = (float)((t01 >> 5) & 63u), g11 = (float)((t11 >> 5) & 63u);
            float b00 = (float)(t00 & 31u),        b10 = (float)(t10 & 31u);
            float b01 = (float)(t01 & 31u),        b11 = (float)(t11 & 31u);

            float sr = r00*w00 + r10*w10 + r01*w01 + r11*w11;
            float sg = g00*w00 + g10*w10 + g01*w01 + g11*w11;
            float sb = b00*w00 + b10*w10 + b01*w01 + b11*w11;

            bool m = !((sr == 0.0f) && (sg == 0.0f) && (sb == 0.0f));

            float d0 = fmaf(sr, 1.0f / 31.0f, -r0);
            float d1 = fmaf(sg, 1.0f / 63.0f, -r1);
            float d2 = fmaf(sb, 1.0f / 31.0f, -r2);
            float per = sqrtf(d0*d0 + d1*d1 + d2*d2);

            accs[nb] += m ? per : 0.0f;
            cnl[nb]  += m ? 1.0f : 0.0f;
        }
    }

    // wave(64) shuffle reduce per batch, then LDS across 4 waves, then atomics
    __shared__ float lsum[4][NB], lcnt[4][NB];
    int wid = tid >> 6;
    int lane = tid & 63;
    #pragma unroll
    for (int nb = 0; nb < NB; ++nb) {
        float a = accs[nb], c = cnl[nb];
        #pragma unroll
        for (int off = 32; off > 0; off >>= 1) {
            a += __shfl_down(a, off, 64);
            c += __shfl_down(c, off, 64);
        }
        if (lane == 0) { lsum[wid][nb] = a; lcnt[wid][nb] = c; }
    }
    __syncthreads();
    if (tid < NB * 2) {
        int nb = tid & (NB - 1);
        int k = tid >> 3;   // 0 = sum, 1 = cnt
        float v = 0.f;
        #pragma unroll
        for (int w = 0; w < 4; ++w) v += k ? lcnt[w][nb] : lsum[w][nb];
        atomicAdd(k ? &cnts[b0 + nb] : &sums[b0 + nb], v);
    }
}

__global__ void bsl_finalize(const float* __restrict__ sums,
                             const float* __restrict__ cnts,
                             float* __restrict__ out,
                             int B) {
    int b = threadIdx.x;  // 0..63
    float loss = 0.f;
    if (b < B) {
        loss = sums[b] / cnts[b];
        out[1 + b] = loss;
    }
    #pragma unroll
    for (int off = 32; off > 0; off >>= 1)
        loss += __shfl_down(loss, off, 64);
    if (b == 0) out[0] = loss;
}

extern "C" void kernel_launch(void* const* d_in, const int* in_sizes, int n_in,
                              void* d_out, int out_size, void* d_ws, size_t ws_size,
                              hipStream_t stream) {
    const float* xyz   = (const float*)d_in[0];
    const float* rgb   = (const float*)d_in[1];
    const float* img   = (const float*)d_in[2];
    const float* trans = (const float*)d_in[3];
    const float* yaw   = (const float*)d_in[4];
    const float* pitch = (const float*)d_in[5];
    const float* roll  = (const float*)d_in[6];
    float* out = (float*)d_out;

    const int n_pts = in_sizes[0] / 3;      // 200000
    const int B     = in_sizes[3] / 3;      // 32

    float* ws   = (float*)d_ws;
    float* rm   = ws;               // 9*B floats
    float* sums = ws + 9 * B;       // B floats
    float* cnts = ws + 10 * B;      // B floats
    uint32_t* vp2 = (uint32_t*)((char*)d_ws + 2048);  // 4 MB

    bsl_pack_setup<<<IMG_H / 2, 256, 0, stream>>>(
        img, vp2, yaw, pitch, roll, rm, sums, cnts, B);

    dim3 grid((n_pts + 255) / 256, B / NB);
    bsl_main<<<grid, 256, 0, stream>>>(xyz, rgb, vp2, trans, rm, sums, cnts, n_pts);

    bsl_finalize<<<1, 64, 0, stream>>>(sums, cnts, out, B);
}